// Round 1
// baseline (24315.875 us; speedup 1.0000x reference)
//
#include <hip/hip_runtime.h>
#include <cstdint>
#include <cstddef>

#define NB 32
#define NT 64
#define NV 32000
#define NE 512
#define NH 1024
#define BOS_ID 1
#define EOS_ID 3
#define KC 64
#define VB 64

__device__ __forceinline__ unsigned mono_f32(float f) {
    unsigned u = __float_as_uint(f);
    return (u & 0x80000000u) ? ~u : (u | 0x80000000u);
}

// h0 = img @ Wp^T + bp ; c = 0
__global__ __launch_bounds__(256) void k_init(const float* __restrict__ img,
                                              const float* __restrict__ Wp,
                                              const float* __restrict__ bp,
                                              float* __restrict__ h0,
                                              float* __restrict__ c) {
    int g = blockIdx.x * 256 + threadIdx.x;   // 32768 outputs, one per thread
    int j = g >> 5, b = g & 31;
    const float* ir = img + (size_t)b * NH;   // D == 1024
    const float* wr = Wp + (size_t)j * NH;
    float s = bp[j];
    for (int k = 0; k < NH; k++) s = fmaf(ir[k], wr[k], s);
    h0[b * NH + j] = s;
    c[b * NH + j]  = 0.0f;
}

// logits + gumbel + argmax partial via device atomicMax.
// v2: 500 blocks x 512 threads; 64 v-cols/block; KC=64 double-buffered.
// 2 blocks/CU (52KB LDS) -> 16 waves/CU for latency hiding.
// Per-thread tile 4b x 4v, 4-way k-split per chunk, shfl_xor kq-reduce.
// LDS col swizzle col ^= ((kk>>2)&7)<<2 (+ kq bit for hs): staging stores
// 8-way -> 2-way bank conflict; reads stay at bandwidth floor.
__global__ __launch_bounds__(512, 4) void k_logit(const float* __restrict__ h,
                                                  const float* __restrict__ Whv,
                                                  const float* __restrict__ bhv,
                                                  const float* __restrict__ gu,
                                                  int s,
                                                  unsigned long long* __restrict__ slot) {
    __shared__ __align__(16) float wsh[2][KC][68];  // [buf][k][v^swz], stride 68
    __shared__ __align__(16) float hs[2][KC][36];   // [buf][k][b^swz], stride 36
    const int tid  = threadIdx.x;
    const int v0   = blockIdx.x * VB;
    const int lane = tid & 63;
    const int wb   = tid >> 6;        // wave 0..7 -> b-group (b = 4*wb + kq)
    const int kq   = lane >> 4;       // 0..3: k-quarter within chunk
    const int sv   = lane & 15;       // v-group of 4 (all 64 v within wave)

    // staging map (512 threads cover 64k x 64v W-tile + 64k x 32b h-tile)
    const int wq  = tid & 15;         // k-quad within chunk (k = wq*4 + j)
    const int wv  = tid >> 4;         // 0..31
    const int mst = (wq & 7) << 2;    // col swizzle: ((kk>>2)&7)<<2 with kk=wq*4+j
    const int kqs = ((wq >> 2) & 1) << 4;  // hs extra swizzle: ((kk>>4)&1)<<4

    float4 wr[2];
    float4 hr;
    float acc[4][4];                  // [bi][vj]
#pragma unroll
    for (int bi = 0; bi < 4; bi++)
#pragma unroll
        for (int j = 0; j < 4; j++) acc[bi][j] = 0.f;

    auto load_chunk = [&](int kc) {
#pragma unroll
        for (int i = 0; i < 2; i++) {
            int vv = i * 32 + wv;
            wr[i] = *(const float4*)&Whv[(size_t)(v0 + vv) * NH + kc + wq * 4];
        }
        hr = *(const float4*)&h[wv * NH + kc + wq * 4];   // wv==b for h staging
    };
    auto store_chunk = [&](int p) {
#pragma unroll
        for (int i = 0; i < 2; i++) {
            int cb = (i * 32 + wv) ^ mst;
            wsh[p][wq * 4 + 0][cb] = wr[i].x;
            wsh[p][wq * 4 + 1][cb] = wr[i].y;
            wsh[p][wq * 4 + 2][cb] = wr[i].z;
            wsh[p][wq * 4 + 3][cb] = wr[i].w;
        }
        int ch = (wv ^ mst) ^ kqs;
        hs[p][wq * 4 + 0][ch] = hr.x;
        hs[p][wq * 4 + 1][ch] = hr.y;
        hs[p][wq * 4 + 2][ch] = hr.z;
        hs[p][wq * 4 + 3][ch] = hr.w;
    };

    load_chunk(0);
    store_chunk(0);
    load_chunk(KC);                      // chunk 1 -> regs (in flight / held)

    const int NCH = NH / KC;             // 16
    for (int cc = 0; cc < NCH; cc++) {
        __syncthreads();                 // LDS[cc&1] ready for all waves
        const int p = cc & 1;
#pragma unroll
        for (int i = 0; i < 16; i++) {
            const int kk = kq * 16 + i;
            const int m4 = (((kq << 2) + (i >> 2)) & 7) << 2;   // ((kk>>2)&7)<<2
            const float4 w4 = *(const float4*)&wsh[p][kk][(sv << 2) ^ m4];
            const float4 h4 = *(const float4*)&hs[p][kk][((wb << 2) ^ m4) ^ ((kq & 1) << 4)];
            acc[0][0] = fmaf(h4.x, w4.x, acc[0][0]);
            acc[0][1] = fmaf(h4.x, w4.y, acc[0][1]);
            acc[0][2] = fmaf(h4.x, w4.z, acc[0][2]);
            acc[0][3] = fmaf(h4.x, w4.w, acc[0][3]);
            acc[1][0] = fmaf(h4.y, w4.x, acc[1][0]);
            acc[1][1] = fmaf(h4.y, w4.y, acc[1][1]);
            acc[1][2] = fmaf(h4.y, w4.z, acc[1][2]);
            acc[1][3] = fmaf(h4.y, w4.w, acc[1][3]);
            acc[2][0] = fmaf(h4.z, w4.x, acc[2][0]);
            acc[2][1] = fmaf(h4.z, w4.y, acc[2][1]);
            acc[2][2] = fmaf(h4.z, w4.z, acc[2][2]);
            acc[2][3] = fmaf(h4.z, w4.w, acc[2][3]);
            acc[3][0] = fmaf(h4.w, w4.x, acc[3][0]);
            acc[3][1] = fmaf(h4.w, w4.y, acc[3][1]);
            acc[3][2] = fmaf(h4.w, w4.z, acc[3][2]);
            acc[3][3] = fmaf(h4.w, w4.w, acc[3][3]);
        }
        if (cc + 1 < NCH) {
            store_chunk(1 - p);                       // waits vmcnt for regs
            if (cc + 2 < NCH) load_chunk((cc + 2) * KC);
        }
    }

    // kq-reduce: partners lane^16, lane^32; order (a0+a1)+(a2+a3), all lanes equal
    float* af = &acc[0][0];
#pragma unroll
    for (int r = 0; r < 16; r++) {
        af[r] += __shfl_xor(af[r], 16, 64);
        af[r] += __shfl_xor(af[r], 32, 64);
    }

    // epilogue: lane handles b = 4*wb + kq, v = v0 + 4*sv + j
    const int b = (wb << 2) + kq;
    float accsel[4];
#pragma unroll
    for (int j = 0; j < 4; j++)
        accsel[j] = (kq == 0) ? acc[0][j] : (kq == 1) ? acc[1][j]
                   : (kq == 2) ? acc[2][j] : acc[3][j];

    const float4 bv4 = *(const float4*)&bhv[v0 + (sv << 2)];
    const float bvv[4] = {bv4.x, bv4.y, bv4.z, bv4.w};
    const float4 u4 = *(const float4*)&gu[((size_t)s * NB + b) * NV + v0 + (sv << 2)];
    const float uvv[4] = {u4.x, u4.y, u4.z, u4.w};
    float best = -3.4e38f;
    int bidx = v0 + (sv << 2);
#pragma unroll
    for (int j = 0; j < 4; j++) {
        float g  = -logf(-logf(uvv[j] + 1e-10f) + 1e-10f);
        float sc = accsel[j] + bvv[j] + g;      // TAU == 1.0
        if (sc > best) { best = sc; bidx = v0 + (sv << 2) + j; }
    }
    unsigned long long key =
        ((unsigned long long)mono_f32(best) << 32) | (unsigned)(~(unsigned)bidx);
#pragma unroll
    for (int m = 1; m < 16; m <<= 1) {
        unsigned long long o =
            (unsigned long long)__shfl_xor((long long)key, m, 64);
        if (o > key) key = o;
    }
    if (sv == 0) atomicMax(&slot[(s & 1) * 32 + b], key);
}

// argmax-finalize (read slots) + LSTM cell slice (4 h-outputs per block)
__global__ __launch_bounds__(256) void k_lstm(const float* __restrict__ h,
                                              float* __restrict__ hn,
                                              float* __restrict__ cbuf,
                                              const float* __restrict__ emb,
                                              const float* __restrict__ Wih,
                                              const float* __restrict__ Whh,
                                              const float* __restrict__ bih,
                                              const float* __restrict__ bhh,
                                              unsigned long long* __restrict__ slot,
                                              int* __restrict__ hist,
                                              int s, int skip) {
    __shared__ float Wt[512][20];   // [k][slot], stride 20: aligned f4, conflict-free reads
    __shared__ float xh[32][517];   // [b][k], stride 517: 2-way max on reads
    __shared__ int labels[32];
    const int tid = threadIdx.x, blk = blockIdx.x;
    const int b8 = tid >> 3, ks = tid & 7;

    if (s < 0) {
        if (tid < 32) labels[tid] = BOS_ID;
    } else {
        if (tid < 32) labels[tid] = (int)(~(unsigned)slot[(s & 1) * 32 + tid]);
    }
    if (tid >= 32 && tid < 64)
        slot[((s + 1) & 1) * 32 + (tid - 32)] = 0ull;   // pre-zero next parity
    if (s >= 0 && blk == 0 && tid < 32) hist[s * 32 + tid] = labels[tid];
    if (skip) return;

    const int j0 = blk * 4;
    float acc[16];
#pragma unroll
    for (int r = 0; r < 16; r++) acc[r] = 0.f;

    for (int chunk = 0; chunk < 3; chunk++) {
        __syncthreads();
#pragma unroll
        for (int i = 0; i < 32; i++) {     // stage 16 gate rows x 512 k
            int idx = i * 256 + tid;
            int slot_i = idx >> 9, k = idx & 511;
            int gate = slot_i >> 2, jj = slot_i & 3;
            int row = gate * NH + j0 + jj;
            float w = (chunk == 0) ? Wih[(size_t)row * NE + k]
                                   : Whh[(size_t)row * NH + (chunk - 1) * 512 + k];
            Wt[k][slot_i] = w;
        }
#pragma unroll
        for (int i = 0; i < 64; i++) {     // stage x / h chunk
            int idx = i * 256 + tid;
            int b = idx >> 9, k = idx & 511;
            float xv = (chunk == 0) ? emb[(size_t)labels[b] * NE + k]
                                    : h[b * NH + (chunk - 1) * 512 + k];
            xh[b][k] = xv;
        }
        __syncthreads();
#pragma unroll 4
        for (int i = 0; i < 64; i++) {
            int k = ks + 8 * i;
            float xv = xh[b8][k];
            const float4 w0 = *(const float4*)&Wt[k][0];
            const float4 w1 = *(const float4*)&Wt[k][4];
            const float4 w2 = *(const float4*)&Wt[k][8];
            const float4 w3 = *(const float4*)&Wt[k][12];
            acc[0]  = fmaf(xv, w0.x, acc[0]);  acc[1]  = fmaf(xv, w0.y, acc[1]);
            acc[2]  = fmaf(xv, w0.z, acc[2]);  acc[3]  = fmaf(xv, w0.w, acc[3]);
            acc[4]  = fmaf(xv, w1.x, acc[4]);  acc[5]  = fmaf(xv, w1.y, acc[5]);
            acc[6]  = fmaf(xv, w1.z, acc[6]);  acc[7]  = fmaf(xv, w1.w, acc[7]);
            acc[8]  = fmaf(xv, w2.x, acc[8]);  acc[9]  = fmaf(xv, w2.y, acc[9]);
            acc[10] = fmaf(xv, w2.z, acc[10]); acc[11] = fmaf(xv, w2.w, acc[11]);
            acc[12] = fmaf(xv, w3.x, acc[12]); acc[13] = fmaf(xv, w3.y, acc[13]);
            acc[14] = fmaf(xv, w3.z, acc[14]); acc[15] = fmaf(xv, w3.w, acc[15]);
        }
    }
#pragma unroll
    for (int m = 1; m < 8; m <<= 1)
#pragma unroll
        for (int r = 0; r < 16; r++) acc[r] += __shfl_xor(acc[r], m, 64);

    if (ks == 0) {
        int b = b8;
#pragma unroll
        for (int jj = 0; jj < 4; jj++) {
            int j = j0 + jj;
            float gi = acc[0 + jj]  + bih[j]          + bhh[j];
            float gf = acc[4 + jj]  + bih[NH + j]     + bhh[NH + j];
            float gg = acc[8 + jj]  + bih[2 * NH + j] + bhh[2 * NH + j];
            float go = acc[12 + jj] + bih[3 * NH + j] + bhh[3 * NH + j];
            float si = 1.f / (1.f + expf(-gi));
            float sf = 1.f / (1.f + expf(-gf));
            float so = 1.f / (1.f + expf(-go));
            float cn = sf * cbuf[b * NH + j] + si * tanhf(gg);
            float hv = so * tanhf(cn);
            cbuf[b * NH + j] = cn;
            hn[b * NH + j]   = hv;
        }
    }
}

// ids / lengths from label history
__global__ __launch_bounds__(64) void k_out(const int* __restrict__ hist,
                                            float* __restrict__ out) {
    int b = threadIdx.x;
    if (b >= 32) return;
    int te = 63;   // first EOS index (t=63 forced EOS)
    for (int t = 0; t < 63; t++)
        if (hist[t * 32 + b] == EOS_ID) { te = t; break; }
    for (int t = 0; t < 64; t++) {
        int lab = (t < 63) ? hist[t * 32 + b] : EOS_ID;
        int id = (t < te) ? lab : 0;           // pad_g true strictly before first EOS
        out[b * 64 + t] = (float)id;
    }
    out[2048 + (size_t)NB * NT * NV + b] = (float)(te + 1);
}

// zero logits region + scatter one-hot (message_logits == one_hot(message_ids))
__global__ __launch_bounds__(256) void k_scatter(float* __restrict__ out) {
    const int bt = blockIdx.x;                 // b*64 + t
    float* row = out + 2048 + (size_t)bt * NV;
    const int id = (int)out[bt];               // ids already written by k_out
    float4 z = make_float4(0.f, 0.f, 0.f, 0.f);
    for (int i = threadIdx.x; i < NV / 4; i += 256) ((float4*)row)[i] = z;
    __syncthreads();
    if (threadIdx.x == 0) row[id] = 1.0f;
}

extern "C" void kernel_launch(void* const* d_in, const int* in_sizes, int n_in,
                              void* d_out, int out_size, void* d_ws, size_t ws_size,
                              hipStream_t stream) {
    const float* img = (const float*)d_in[0];
    const float* gu  = (const float*)d_in[1];
    const float* Wp  = (const float*)d_in[2];
    const float* bp  = (const float*)d_in[3];
    const float* emb = (const float*)d_in[4];
    const float* Wih = (const float*)d_in[5];
    const float* Whh = (const float*)d_in[6];
    const float* bih = (const float*)d_in[7];
    const float* bhh = (const float*)d_in[8];
    const float* Whv = (const float*)d_in[9];
    const float* bhv = (const float*)d_in[10];
    float* out = (float*)d_out;

    // scratch lives inside the logits region of d_out (fully overwritten by k_scatter)
    float* scratch = out + 2048;
    float* hA = scratch;                 // 32768
    float* hB = scratch + 32768;         // 32768
    float* cb = scratch + 65536;         // 32768
    unsigned long long* slot = (unsigned long long*)(scratch + 98304); // 64 u64 (2 parities)
    int* hist = (int*)(scratch + 98304 + 128);                         // 63*32 ints

    k_init<<<128, 256, 0, stream>>>(img, Wp, bp, hB, cb);
    // initial LSTM cell with x0 = emb[BOS], h = h0, c = 0 -> writes hA; zeroes slot parity 0
    k_lstm<<<256, 256, 0, stream>>>(hB, hA, cb, emb, Wih, Whh, bih, bhh,
                                    slot, hist, -1, 0);
    for (int s = 0; s < 63; s++) {
        const float* hc = (s & 1) ? hB : hA;
        float* hn       = (s & 1) ? hA : hB;
        k_logit<<<500, 512, 0, stream>>>(hc, Whv, bhv, gu, s, slot);
        k_lstm<<<256, 256, 0, stream>>>(hc, hn, cb, emb, Wih, Whh, bih, bhh,
                                        slot, hist, s, (s == 62) ? 1 : 0);
    }
    k_out<<<1, 64, 0, stream>>>(hist, out);
    k_scatter<<<2048, 256, 0, stream>>>(out);
}

// Round 2
// 11979.308 us; speedup vs baseline: 2.0298x; 2.0298x over previous
//
#include <hip/hip_runtime.h>
#include <cstdint>
#include <cstddef>

#define NB 32
#define NT 64
#define NV 32000
#define NE 512
#define NH 1024
#define BOS_ID 1
#define EOS_ID 3
#define KC 64
#define VB 64

__device__ __forceinline__ unsigned mono_f32(float f) {
    unsigned u = __float_as_uint(f);
    return (u & 0x80000000u) ? ~u : (u | 0x80000000u);
}

// h0 = img @ Wp^T + bp ; c = 0
__global__ __launch_bounds__(256) void k_init(const float* __restrict__ img,
                                              const float* __restrict__ Wp,
                                              const float* __restrict__ bp,
                                              float* __restrict__ h0,
                                              float* __restrict__ c) {
    int g = blockIdx.x * 256 + threadIdx.x;   // 32768 outputs, one per thread
    int j = g >> 5, b = g & 31;
    const float* ir = img + (size_t)b * NH;   // D == 1024
    const float* wr = Wp + (size_t)j * NH;
    float s = bp[j];
    for (int k = 0; k < NH; k++) s = fmaf(ir[k], wr[k], s);
    h0[b * NH + j] = s;
    c[b * NH + j]  = 0.0f;
}

// logits + gumbel + argmax partial via device atomicMax.
// v3: same structure as v2 (500 blocks x 512 threads; 64 v-cols/block; KC=64
// double-buffered; 4b x 4v per-thread tile; kq-split + shfl reduce; XOR swizzle)
// BUT launch bounds relaxed: v2's __launch_bounds__(512,4) clamped to 64 VGPR ->
// acc spilled to scratch -> 682 MB/dispatch HBM writes, 338 us. Let allocator
// take ~96-128 VGPR (still 4 waves/SIMD = 2 blocks/CU with 52KB LDS).
__global__ __launch_bounds__(512) void k_logit(const float* __restrict__ h,
                                               const float* __restrict__ Whv,
                                               const float* __restrict__ bhv,
                                               const float* __restrict__ gu,
                                               int s,
                                               unsigned long long* __restrict__ slot) {
    __shared__ __align__(16) float wsh[2][KC][68];  // [buf][k][v^swz], stride 68
    __shared__ __align__(16) float hs[2][KC][36];   // [buf][k][b^swz], stride 36
    const int tid  = threadIdx.x;
    const int v0   = blockIdx.x * VB;
    const int lane = tid & 63;
    const int wb   = tid >> 6;        // wave 0..7 -> b-group (b = 4*wb + kq)
    const int kq   = lane >> 4;       // 0..3: k-quarter within chunk
    const int sv   = lane & 15;       // v-group of 4 (all 64 v within wave)

    // staging map (512 threads cover 64k x 64v W-tile + 64k x 32b h-tile)
    const int wq  = tid & 15;         // k-quad within chunk (k = wq*4 + j)
    const int wv  = tid >> 4;         // 0..31
    const int mst = (wq & 7) << 2;    // col swizzle: ((kk>>2)&7)<<2 with kk=wq*4+j
    const int kqs = ((wq >> 2) & 1) << 4;  // hs extra swizzle: ((kk>>4)&1)<<4

    float4 wr[2];
    float4 hr;
    float acc[4][4];                  // [bi][vj]
#pragma unroll
    for (int bi = 0; bi < 4; bi++)
#pragma unroll
        for (int j = 0; j < 4; j++) acc[bi][j] = 0.f;

    auto load_chunk = [&](int kc) {
#pragma unroll
        for (int i = 0; i < 2; i++) {
            int vv = i * 32 + wv;
            wr[i] = *(const float4*)&Whv[(size_t)(v0 + vv) * NH + kc + wq * 4];
        }
        hr = *(const float4*)&h[wv * NH + kc + wq * 4];   // wv==b for h staging
    };
    auto store_chunk = [&](int p) {
#pragma unroll
        for (int i = 0; i < 2; i++) {
            int cb = (i * 32 + wv) ^ mst;
            wsh[p][wq * 4 + 0][cb] = wr[i].x;
            wsh[p][wq * 4 + 1][cb] = wr[i].y;
            wsh[p][wq * 4 + 2][cb] = wr[i].z;
            wsh[p][wq * 4 + 3][cb] = wr[i].w;
        }
        int ch = (wv ^ mst) ^ kqs;
        hs[p][wq * 4 + 0][ch] = hr.x;
        hs[p][wq * 4 + 1][ch] = hr.y;
        hs[p][wq * 4 + 2][ch] = hr.z;
        hs[p][wq * 4 + 3][ch] = hr.w;
    };

    load_chunk(0);
    store_chunk(0);
    load_chunk(KC);                      // chunk 1 -> regs (in flight / held)

    const int NCH = NH / KC;             // 16
    for (int cc = 0; cc < NCH; cc++) {
        __syncthreads();                 // LDS[cc&1] ready for all waves
        const int p = cc & 1;
#pragma unroll
        for (int i = 0; i < 16; i++) {
            const int kk = kq * 16 + i;
            const int m4 = (((kq << 2) + (i >> 2)) & 7) << 2;   // ((kk>>2)&7)<<2
            const float4 w4 = *(const float4*)&wsh[p][kk][(sv << 2) ^ m4];
            const float4 h4 = *(const float4*)&hs[p][kk][((wb << 2) ^ m4) ^ ((kq & 1) << 4)];
            acc[0][0] = fmaf(h4.x, w4.x, acc[0][0]);
            acc[0][1] = fmaf(h4.x, w4.y, acc[0][1]);
            acc[0][2] = fmaf(h4.x, w4.z, acc[0][2]);
            acc[0][3] = fmaf(h4.x, w4.w, acc[0][3]);
            acc[1][0] = fmaf(h4.y, w4.x, acc[1][0]);
            acc[1][1] = fmaf(h4.y, w4.y, acc[1][1]);
            acc[1][2] = fmaf(h4.y, w4.z, acc[1][2]);
            acc[1][3] = fmaf(h4.y, w4.w, acc[1][3]);
            acc[2][0] = fmaf(h4.z, w4.x, acc[2][0]);
            acc[2][1] = fmaf(h4.z, w4.y, acc[2][1]);
            acc[2][2] = fmaf(h4.z, w4.z, acc[2][2]);
            acc[2][3] = fmaf(h4.z, w4.w, acc[2][3]);
            acc[3][0] = fmaf(h4.w, w4.x, acc[3][0]);
            acc[3][1] = fmaf(h4.w, w4.y, acc[3][1]);
            acc[3][2] = fmaf(h4.w, w4.z, acc[3][2]);
            acc[3][3] = fmaf(h4.w, w4.w, acc[3][3]);
        }
        if (cc + 1 < NCH) {
            store_chunk(1 - p);                       // waits vmcnt for regs
            if (cc + 2 < NCH) load_chunk((cc + 2) * KC);
        }
    }

    // kq-reduce: partners lane^16, lane^32; order (a0+a1)+(a2+a3), all lanes equal
    float* af = &acc[0][0];
#pragma unroll
    for (int r = 0; r < 16; r++) {
        af[r] += __shfl_xor(af[r], 16, 64);
        af[r] += __shfl_xor(af[r], 32, 64);
    }

    // epilogue: lane handles b = 4*wb + kq, v = v0 + 4*sv + j
    const int b = (wb << 2) + kq;
    float accsel[4];
#pragma unroll
    for (int j = 0; j < 4; j++)
        accsel[j] = (kq == 0) ? acc[0][j] : (kq == 1) ? acc[1][j]
                   : (kq == 2) ? acc[2][j] : acc[3][j];

    const float4 bv4 = *(const float4*)&bhv[v0 + (sv << 2)];
    const float bvv[4] = {bv4.x, bv4.y, bv4.z, bv4.w};
    const float4 u4 = *(const float4*)&gu[((size_t)s * NB + b) * NV + v0 + (sv << 2)];
    const float uvv[4] = {u4.x, u4.y, u4.z, u4.w};
    float best = -3.4e38f;
    int bidx = v0 + (sv << 2);
#pragma unroll
    for (int j = 0; j < 4; j++) {
        float g  = -logf(-logf(uvv[j] + 1e-10f) + 1e-10f);
        float sc = accsel[j] + bvv[j] + g;      // TAU == 1.0
        if (sc > best) { best = sc; bidx = v0 + (sv << 2) + j; }
    }
    unsigned long long key =
        ((unsigned long long)mono_f32(best) << 32) | (unsigned)(~(unsigned)bidx);
#pragma unroll
    for (int m = 1; m < 16; m <<= 1) {
        unsigned long long o =
            (unsigned long long)__shfl_xor((long long)key, m, 64);
        if (o > key) key = o;
    }
    if (sv == 0) atomicMax(&slot[(s & 1) * 32 + b], key);
}

// argmax-finalize (read slots) + LSTM cell slice (4 h-outputs per block)
__global__ __launch_bounds__(256) void k_lstm(const float* __restrict__ h,
                                              float* __restrict__ hn,
                                              float* __restrict__ cbuf,
                                              const float* __restrict__ emb,
                                              const float* __restrict__ Wih,
                                              const float* __restrict__ Whh,
                                              const float* __restrict__ bih,
                                              const float* __restrict__ bhh,
                                              unsigned long long* __restrict__ slot,
                                              int* __restrict__ hist,
                                              int s, int skip) {
    __shared__ float Wt[512][20];   // [k][slot], stride 20: aligned f4, conflict-free reads
    __shared__ float xh[32][517];   // [b][k], stride 517: 2-way max on reads
    __shared__ int labels[32];
    const int tid = threadIdx.x, blk = blockIdx.x;
    const int b8 = tid >> 3, ks = tid & 7;

    if (s < 0) {
        if (tid < 32) labels[tid] = BOS_ID;
    } else {
        if (tid < 32) labels[tid] = (int)(~(unsigned)slot[(s & 1) * 32 + tid]);
    }
    if (tid >= 32 && tid < 64)
        slot[((s + 1) & 1) * 32 + (tid - 32)] = 0ull;   // pre-zero next parity
    if (s >= 0 && blk == 0 && tid < 32) hist[s * 32 + tid] = labels[tid];
    if (skip) return;

    const int j0 = blk * 4;
    float acc[16];
#pragma unroll
    for (int r = 0; r < 16; r++) acc[r] = 0.f;

    for (int chunk = 0; chunk < 3; chunk++) {
        __syncthreads();
#pragma unroll
        for (int i = 0; i < 32; i++) {     // stage 16 gate rows x 512 k
            int idx = i * 256 + tid;
            int slot_i = idx >> 9, k = idx & 511;
            int gate = slot_i >> 2, jj = slot_i & 3;
            int row = gate * NH + j0 + jj;
            float w = (chunk == 0) ? Wih[(size_t)row * NE + k]
                                   : Whh[(size_t)row * NH + (chunk - 1) * 512 + k];
            Wt[k][slot_i] = w;
        }
#pragma unroll
        for (int i = 0; i < 64; i++) {     // stage x / h chunk
            int idx = i * 256 + tid;
            int b = idx >> 9, k = idx & 511;
            float xv = (chunk == 0) ? emb[(size_t)labels[b] * NE + k]
                                    : h[b * NH + (chunk - 1) * 512 + k];
            xh[b][k] = xv;
        }
        __syncthreads();
#pragma unroll 4
        for (int i = 0; i < 64; i++) {
            int k = ks + 8 * i;
            float xv = xh[b8][k];
            const float4 w0 = *(const float4*)&Wt[k][0];
            const float4 w1 = *(const float4*)&Wt[k][4];
            const float4 w2 = *(const float4*)&Wt[k][8];
            const float4 w3 = *(const float4*)&Wt[k][12];
            acc[0]  = fmaf(xv, w0.x, acc[0]);  acc[1]  = fmaf(xv, w0.y, acc[1]);
            acc[2]  = fmaf(xv, w0.z, acc[2]);  acc[3]  = fmaf(xv, w0.w, acc[3]);
            acc[4]  = fmaf(xv, w1.x, acc[4]);  acc[5]  = fmaf(xv, w1.y, acc[5]);
            acc[6]  = fmaf(xv, w1.z, acc[6]);  acc[7]  = fmaf(xv, w1.w, acc[7]);
            acc[8]  = fmaf(xv, w2.x, acc[8]);  acc[9]  = fmaf(xv, w2.y, acc[9]);
            acc[10] = fmaf(xv, w2.z, acc[10]); acc[11] = fmaf(xv, w2.w, acc[11]);
            acc[12] = fmaf(xv, w3.x, acc[12]); acc[13] = fmaf(xv, w3.y, acc[13]);
            acc[14] = fmaf(xv, w3.z, acc[14]); acc[15] = fmaf(xv, w3.w, acc[15]);
        }
    }
#pragma unroll
    for (int m = 1; m < 8; m <<= 1)
#pragma unroll
        for (int r = 0; r < 16; r++) acc[r] += __shfl_xor(acc[r], m, 64);

    if (ks == 0) {
        int b = b8;
#pragma unroll
        for (int jj = 0; jj < 4; jj++) {
            int j = j0 + jj;
            float gi = acc[0 + jj]  + bih[j]          + bhh[j];
            float gf = acc[4 + jj]  + bih[NH + j]     + bhh[NH + j];
            float gg = acc[8 + jj]  + bih[2 * NH + j] + bhh[2 * NH + j];
            float go = acc[12 + jj] + bih[3 * NH + j] + bhh[3 * NH + j];
            float si = 1.f / (1.f + expf(-gi));
            float sf = 1.f / (1.f + expf(-gf));
            float so = 1.f / (1.f + expf(-go));
            float cn = sf * cbuf[b * NH + j] + si * tanhf(gg);
            float hv = so * tanhf(cn);
            cbuf[b * NH + j] = cn;
            hn[b * NH + j]   = hv;
        }
    }
}

// ids / lengths from label history
__global__ __launch_bounds__(64) void k_out(const int* __restrict__ hist,
                                            float* __restrict__ out) {
    int b = threadIdx.x;
    if (b >= 32) return;
    int te = 63;   // first EOS index (t=63 forced EOS)
    for (int t = 0; t < 63; t++)
        if (hist[t * 32 + b] == EOS_ID) { te = t; break; }
    for (int t = 0; t < 64; t++) {
        int lab = (t < 63) ? hist[t * 32 + b] : EOS_ID;
        int id = (t < te) ? lab : 0;           // pad_g true strictly before first EOS
        out[b * 64 + t] = (float)id;
    }
    out[2048 + (size_t)NB * NT * NV + b] = (float)(te + 1);
}

// zero logits region + scatter one-hot (message_logits == one_hot(message_ids))
__global__ __launch_bounds__(256) void k_scatter(float* __restrict__ out) {
    const int bt = blockIdx.x;                 // b*64 + t
    float* row = out + 2048 + (size_t)bt * NV;
    const int id = (int)out[bt];               // ids already written by k_out
    float4 z = make_float4(0.f, 0.f, 0.f, 0.f);
    for (int i = threadIdx.x; i < NV / 4; i += 256) ((float4*)row)[i] = z;
    __syncthreads();
    if (threadIdx.x == 0) row[id] = 1.0f;
}

extern "C" void kernel_launch(void* const* d_in, const int* in_sizes, int n_in,
                              void* d_out, int out_size, void* d_ws, size_t ws_size,
                              hipStream_t stream) {
    const float* img = (const float*)d_in[0];
    const float* gu  = (const float*)d_in[1];
    const float* Wp  = (const float*)d_in[2];
    const float* bp  = (const float*)d_in[3];
    const float* emb = (const float*)d_in[4];
    const float* Wih = (const float*)d_in[5];
    const float* Whh = (const float*)d_in[6];
    const float* bih = (const float*)d_in[7];
    const float* bhh = (const float*)d_in[8];
    const float* Whv = (const float*)d_in[9];
    const float* bhv = (const float*)d_in[10];
    float* out = (float*)d_out;

    // scratch lives inside the logits region of d_out (fully overwritten by k_scatter)
    float* scratch = out + 2048;
    float* hA = scratch;                 // 32768
    float* hB = scratch + 32768;         // 32768
    float* cb = scratch + 65536;         // 32768
    unsigned long long* slot = (unsigned long long*)(scratch + 98304); // 64 u64 (2 parities)
    int* hist = (int*)(scratch + 98304 + 128);                         // 63*32 ints

    k_init<<<128, 256, 0, stream>>>(img, Wp, bp, hB, cb);
    // initial LSTM cell with x0 = emb[BOS], h = h0, c = 0 -> writes hA; zeroes slot parity 0
    k_lstm<<<256, 256, 0, stream>>>(hB, hA, cb, emb, Wih, Whh, bih, bhh,
                                    slot, hist, -1, 0);
    for (int s = 0; s < 63; s++) {
        const float* hc = (s & 1) ? hB : hA;
        float* hn       = (s & 1) ? hA : hB;
        k_logit<<<500, 512, 0, stream>>>(hc, Whv, bhv, gu, s, slot);
        k_lstm<<<256, 256, 0, stream>>>(hc, hn, cb, emb, Wih, Whh, bih, bhh,
                                        slot, hist, s, (s == 62) ? 1 : 0);
    }
    k_out<<<1, 64, 0, stream>>>(hist, out);
    k_scatter<<<2048, 256, 0, stream>>>(out);
}